// Round 14
// baseline (92.476 us; speedup 1.0000x reference)
//
#include <hip/hip_runtime.h>
#include <math.h>

#define NN 2048
#define DD 64
#define HH 64

// ---------------------------------------------------------------------------
// Stage 1: u[i][h] = z[i]·Wa[h] + b1[h];  vt[h][j] = z[j]·Wb[h]  (transposed!)
// Plus fused rank-1 terms: a[i] = 0.5*sum_h W2[h]*u[i][h], b[j] likewise on v.
// (unchanged — passing since r9/r13)
// ---------------------------------------------------------------------------
__global__ __launch_bounds__(256) void prep_kernel(
    const float* __restrict__ z, const float* __restrict__ W1,
    const float* __restrict__ b1, const float* __restrict__ W2,
    float* __restrict__ u, float* __restrict__ vt,
    float* __restrict__ a, float* __restrict__ b) {
  __shared__ float zs[8 * DD];
  const int t = threadIdx.x;
  const int i0 = blockIdx.x * 8;
  if (t < 128) {
    reinterpret_cast<float4*>(zs)[t] =
        reinterpret_cast<const float4*>(z + (size_t)i0 * DD)[t];
  }
  __syncthreads();

  const int hs = t & 127;
  const int rg = t >> 7;
  const int h = hs & 63;
  const int side = hs >> 6;
  const float* wrow = W1 + h * (2 * DD) + side * DD;

  float acc0 = 0.f, acc1 = 0.f, acc2 = 0.f, acc3 = 0.f;
#pragma unroll
  for (int d4 = 0; d4 < DD / 4; ++d4) {
    const float4 wv = reinterpret_cast<const float4*>(wrow)[d4];
    const float* z0 = zs + (rg * 4 + 0) * DD + d4 * 4;
    const float* z1 = z0 + DD;
    const float* z2 = z1 + DD;
    const float* z3 = z2 + DD;
    acc0 = fmaf(z0[3], wv.w, fmaf(z0[2], wv.z, fmaf(z0[1], wv.y, fmaf(z0[0], wv.x, acc0))));
    acc1 = fmaf(z1[3], wv.w, fmaf(z1[2], wv.z, fmaf(z1[1], wv.y, fmaf(z1[0], wv.x, acc1))));
    acc2 = fmaf(z2[3], wv.w, fmaf(z2[2], wv.z, fmaf(z2[1], wv.y, fmaf(z2[0], wv.x, acc2))));
    acc3 = fmaf(z3[3], wv.w, fmaf(z3[2], wv.z, fmaf(z3[1], wv.y, fmaf(z3[0], wv.x, acc3))));
  }
  const float bias = side ? 0.0f : b1[h];
  const float s0 = acc0 + bias, s1 = acc1 + bias, s2 = acc2 + bias, s3 = acc3 + bias;
  const int ib = i0 + rg * 4;
  if (side) {
    float* vrow = vt + (size_t)h * NN + ib;  // transposed layout [h][j]
    vrow[0] = s0; vrow[1] = s1; vrow[2] = s2; vrow[3] = s3;
  } else {
    u[(size_t)(ib + 0) * HH + h] = s0;
    u[(size_t)(ib + 1) * HH + h] = s1;
    u[(size_t)(ib + 2) * HH + h] = s2;
    u[(size_t)(ib + 3) * HH + h] = s3;
  }

  const float wh = W2[h];
  float r0 = wh * s0, r1 = wh * s1, r2 = wh * s2, r3 = wh * s3;
#pragma unroll
  for (int m = 1; m < 64; m <<= 1) {
    r0 += __shfl_xor(r0, m);
    r1 += __shfl_xor(r1, m);
    r2 += __shfl_xor(r2, m);
    r3 += __shfl_xor(r3, m);
  }
  if ((t & 63) == 0) {
    float* d2 = side ? b : a;
    d2[ib + 0] = 0.5f * r0;
    d2[ib + 1] = 0.5f * r1;
    d2[ib + 2] = 0.5f * r2;
    d2[ib + 3] = 0.5f * r3;
  }
}

// ---------------------------------------------------------------------------
// Stage 2 (design E2): out[i][j] = sigmoid(a[i]+b[j]+b2
//                                   + 0.5*sum_h W2[h]*|u[i,h]+vt[h,j]|), diag 0.
// Change vs E: 8 i-rows x 2 j-cols per lane (was 4x4).
//   -> vt L2 traffic HALVES: (2048/8)*512KB = 134 MB (~3.8us floor, was 7.7)
//   -> same 4096 waves = 4 waves/SIMD; all loads/stores stay coalesced (b64).
// u via v_readlane SGPR broadcast (correctness-proven in E); no LDS/barriers.
// ---------------------------------------------------------------------------
__global__ __launch_bounds__(256, 4) void pair_kernel(
    const float* __restrict__ u, const float* __restrict__ vt,
    const float* __restrict__ a, const float* __restrict__ b,
    const float* __restrict__ W2, const float* __restrict__ b2,
    float* __restrict__ out) {
  const int t = threadIdx.x;
  const int L = t & 63;                    // lane
  const int w = t >> 6;                    // wave 0..3
  const int i0 = blockIdx.y * 32 + w * 8;  // wave's 8 i-rows
  const int j0 = blockIdx.x * 128;         // block/wave j-tile
  const int jL = j0 + 2 * L;               // lane's 2 consecutive j

  // lane L holds u[i0+m][L]; 8 coalesced 256B loads
  float ur[8];
#pragma unroll
  for (int m = 0; m < 8; ++m) ur[m] = u[(size_t)(i0 + m) * HH + L];

  const float2* vt2 = reinterpret_cast<const float2*>(vt);  // [64][NN/2]
  const int vcol = (j0 >> 1) + L;

  float acc[8][2] = {};
#pragma unroll
  for (int hc = 0; hc < 16; ++hc) {  // 16 chunks of 4 h
    float2 q[4];
#pragma unroll
    for (int hh = 0; hh < 4; ++hh)   // coalesced b64: 2 consecutive j per lane
      q[hh] = vt2[(size_t)(hc * 4 + hh) * (NN / 2) + vcol];
    const float4 wv = *reinterpret_cast<const float4*>(W2 + hc * 4);  // s_load
    const float wa[4] = {wv.x, wv.y, wv.z, wv.w};
#pragma unroll
    for (int hh = 0; hh < 4; ++hh) {
      const int h = hc * 4 + hh;
      const float wh = wa[hh];
#pragma unroll
      for (int m = 0; m < 8; ++m) {
        const float um = __int_as_float(
            __builtin_amdgcn_readlane(__float_as_int(ur[m]), h));  // SGPR bcast
        acc[m][0] = fmaf(wh, fabsf(um + q[hh].x), acc[m][0]);
        acc[m][1] = fmaf(wh, fabsf(um + q[hh].y), acc[m][1]);
      }
    }
  }

  const float bias2 = b2[0];
  const float2 bj = *reinterpret_cast<const float2*>(b + jL);

#pragma unroll
  for (int m = 0; m < 8; ++m) {
    const int i = i0 + m;
    const float ai = a[i] + bias2;
    float r0, r1;
    {
      const float x0 = ai + bj.x + 0.5f * acc[m][0];
      const float x1 = ai + bj.y + 0.5f * acc[m][1];
      r0 = 1.0f / (1.0f + __expf(-x0));
      r1 = 1.0f / (1.0f + __expf(-x1));
    }
    if (i == jL) r0 = 0.0f;
    if (i == jL + 1) r1 = 0.0f;
    *reinterpret_cast<float2*>(out + (size_t)i * NN + jL) = make_float2(r0, r1);
  }
}

extern "C" void kernel_launch(void* const* d_in, const int* in_sizes, int n_in,
                              void* d_out, int out_size, void* d_ws, size_t ws_size,
                              hipStream_t stream) {
  const float* z  = (const float*)d_in[0];
  const float* W1 = (const float*)d_in[1];
  const float* b1 = (const float*)d_in[2];
  const float* W2 = (const float*)d_in[3];
  const float* b2 = (const float*)d_in[4];
  float* out = (float*)d_out;

  float* u  = (float*)d_ws;               // [2048][64]  512 KB
  float* vt = u + (size_t)NN * HH;        // [64][2048]  512 KB (transposed)
  float* a  = vt + (size_t)NN * HH;       // [2048]      8 KB
  float* b  = a + NN;                     // [2048]      8 KB

  prep_kernel<<<NN / 8, 256, 0, stream>>>(z, W1, b1, W2, u, vt, a, b);
  pair_kernel<<<dim3(NN / 128, NN / 32), 256, 0, stream>>>(u, vt, a, b, W2, b2, out);
}